// Round 8
// baseline (221.150 us; speedup 1.0000x reference)
//
#include <hip/hip_runtime.h>
#include <hip/hip_bf16.h>

// Linear attention (BaseMultiHeadAttention_21105469292684)
// M=16, N=2048, C=512, H=8, D=64.
//   K0 : weights fp32 -> bf16 transposed WT[col][k] (all 4)
//   K1 : Q/K/V = softmax-ish(x @ W): BM=64, BN=512 (wave=head), BK=32,
//        2-phase pipeline: stage(t+1) -> compute(t) -> vmcnt(0)+s_barrier.
//        ALL staging via global_load_lds (A as raw fp32, cvt in compute phase).
//   K2 : kv partials = K_h^T V_h over n-chunks (fp32)
//   K3 : WfusedT[m][c][r] = sum_e kv[m,h,d,e] * Wo[h*64+e][c]  (bf16)
//   K4 : out = Q @ Wfused[m] + bo: same 2-phase pattern, BK=32, fp32 out

typedef __bf16 bf16;
typedef __bf16 bf16x8 __attribute__((ext_vector_type(8)));
typedef __bf16 bf16x4 __attribute__((ext_vector_type(4)));
typedef float  f32x4  __attribute__((ext_vector_type(4)));

#define MFMA16(a, b, c) __builtin_amdgcn_mfma_f32_16x16x32_bf16((a), (b), (c), 0, 0, 0)

__device__ inline bf16x8 cvt8(float4 a, float4 b) {
  bf16x8 h;
  h[0] = (bf16)a.x; h[1] = (bf16)a.y; h[2] = (bf16)a.z; h[3] = (bf16)a.w;
  h[4] = (bf16)b.x; h[5] = (bf16)b.y; h[6] = (bf16)b.z; h[7] = (bf16)b.w;
  return h;
}

__device__ inline void glds16(const void* g, void* l) {
  __builtin_amdgcn_global_load_lds((const __attribute__((address_space(1))) void*)g,
                                   (__attribute__((address_space(3))) void*)l, 16, 0, 0);
}

// ---------------- K0: transpose + convert weights (512x512 each) ----------------
__global__ __launch_bounds__(256) void k_prep(const float* __restrict__ w0, const float* __restrict__ w1,
                                              const float* __restrict__ w2, const float* __restrict__ w3,
                                              bf16* __restrict__ t0, bf16* __restrict__ t1,
                                              bf16* __restrict__ t2, bf16* __restrict__ t3)
{
  const float* W = (blockIdx.z == 0) ? w0 : (blockIdx.z == 1) ? w1 : (blockIdx.z == 2) ? w2 : w3;
  bf16*        T = (blockIdx.z == 0) ? t0 : (blockIdx.z == 1) ? t1 : (blockIdx.z == 2) ? t2 : t3;
  __shared__ float lds[64][68];
  const int t = threadIdx.x;
  const int r = t >> 2, c0 = (t & 3) << 4;
  const float* src = W + (size_t)(blockIdx.x * 64 + r) * 512 + blockIdx.y * 64 + c0;
  float4 f0 = ((const float4*)src)[0];
  float4 f1 = ((const float4*)src)[1];
  float4 f2 = ((const float4*)src)[2];
  float4 f3 = ((const float4*)src)[3];
  *(float4*)&lds[r][c0 + 0]  = f0;
  *(float4*)&lds[r][c0 + 4]  = f1;
  *(float4*)&lds[r][c0 + 8]  = f2;
  *(float4*)&lds[r][c0 + 12] = f3;
  __syncthreads();
  bf16 v[16];
#pragma unroll
  for (int s = 0; s < 16; ++s) v[s] = (bf16)lds[c0 + s][r];
  bf16* dst = T + (size_t)(blockIdx.y * 64 + r) * 512 + blockIdx.x * 64 + c0;
  *(bf16x8*)&dst[0] = *(bf16x8*)&v[0];
  *(bf16x8*)&dst[8] = *(bf16x8*)&v[8];
}

// ---------------- K1: fused projection + per-head softmax (2-phase) ----------------
// grid (512,1,3): 512 row-blocks of 64 rows, z = proj. 512 thr = 8 waves; wave = head.
// A: raw fp32 via glds into Af[2][64][32] (8-slot XOR involution; cvt at read).
// B: glds into Bsm[2][512][32] bf16 (4-slot XOR involution, r7-verified).
__global__ __launch_bounds__(512, 2) void k_qkv(const float* __restrict__ xq, const float* __restrict__ xk,
                                                const float* __restrict__ xv,
                                                const bf16* __restrict__ WqT, const bf16* __restrict__ WkT,
                                                const bf16* __restrict__ WvT,
                                                bf16* __restrict__ Qo, bf16* __restrict__ Ko,
                                                bf16* __restrict__ Vo)
{
  const int proj = blockIdx.z;
  const float* X  = (proj == 0) ? xq  : (proj == 1) ? xk  : xv;
  const bf16*  WT = (proj == 0) ? WqT : (proj == 1) ? WkT : WvT;
  bf16*       OUT = (proj == 0) ? Qo  : (proj == 1) ? Ko  : Vo;

  __shared__ float Af[2][2048];     // 2 x 8 KB   ([64][32] fp32)
  __shared__ bf16  Bsm[2][16384];   // 2 x 32 KB  ([512][32] bf16)

  const int t = threadIdx.x;
  const int lane = t & 63, w = t >> 6;          // w = head
  const int g = lane >> 4, li = lane & 15;
  const size_t arow = (size_t)blockIdx.x * 64;

  // A staging: wave w stages rows w*8..+8; lane l -> row w*8+(l>>3), slot l&7 holds
  // source chunk (l&7)^((l>>3)&7)  (involution with row&7)
  const float* asrc = X + (size_t)(arow + w * 8 + (lane >> 3)) * 512
                        + (((lane & 7) ^ ((lane >> 3) & 7)) << 2);
  // B staging: wave w stages its head's 64 rows; slot l&3 holds chunk (l&3)^((l>>3)&3)
  const bf16* bsrc = WT + (size_t)(w * 64 + (lane >> 2)) * 512
                        + (((lane & 3) ^ ((lane >> 3) & 3)) << 3);

  f32x4 acc[4][4] = {};

  // prologue: stage tile 0 into buf 0
#pragma unroll
  for (int j = 0; j < 4; ++j)
    glds16(bsrc + (size_t)j * 16 * 512, (char*)&Bsm[0][0] + w * 4096 + j * 1024);
  glds16(asrc, (char*)&Af[0][0] + w * 1024);
  asm volatile("s_waitcnt vmcnt(0)" ::: "memory");
  __builtin_amdgcn_s_barrier();

#pragma unroll
  for (int kt = 0; kt < 16; ++kt) {
    const int cur = kt & 1;
    if (kt < 15) {   // stage NEXT tile first; latency hides under this tile's compute
#pragma unroll
      for (int j = 0; j < 4; ++j)
        glds16(bsrc + (size_t)j * 16 * 512 + (kt + 1) * 32,
               (char*)&Bsm[cur ^ 1][0] + w * 4096 + j * 1024);
      glds16(asrc + (kt + 1) * 32, (char*)&Af[cur ^ 1][0] + w * 1024);
    }
    // compute tile kt
    bf16x8 af[4], bfr[4];
    const float* Ab = &Af[cur][0];
#pragma unroll
    for (int rt = 0; rt < 4; ++rt) {
      const int r = rt * 16 + li;
      float4 a0 = *(const float4*)&Ab[r * 32 + (((2 * g)    ) ^ (li & 7)) * 4];
      float4 a1 = *(const float4*)&Ab[r * 32 + (((2 * g) | 1) ^ (li & 7)) * 4];
      af[rt] = cvt8(a0, a1);
    }
#pragma unroll
    for (int ct = 0; ct < 4; ++ct)
      bfr[ct] = *(const bf16x8*)&Bsm[cur][(w * 64 + ct * 16 + li) * 32 + (g ^ ((li >> 1) & 3)) * 8];
#pragma unroll
    for (int rt = 0; rt < 4; ++rt)
#pragma unroll
      for (int ct = 0; ct < 4; ++ct)
        acc[rt][ct] = MFMA16(af[rt], bfr[ct], acc[rt][ct]);
    if (kt < 15) {
      asm volatile("s_waitcnt vmcnt(0)" ::: "memory");
      __builtin_amdgcn_s_barrier();
    }
  }

  // epilogue: softmax over the 64 head columns (rows = rt*16+g*4+q, cols = ct*16+li)
#pragma unroll
  for (int rt = 0; rt < 4; ++rt) {
#pragma unroll
    for (int q = 0; q < 4; ++q) {
      float v0 = acc[rt][0][q], v1 = acc[rt][1][q], v2 = acc[rt][2][q], v3 = acc[rt][3][q];
      if (proj < 2) {
        float mx = fmaxf(fmaxf(v0, v1), fmaxf(v2, v3));
        mx = fmaxf(mx, __shfl_xor(mx, 1));
        mx = fmaxf(mx, __shfl_xor(mx, 2));
        mx = fmaxf(mx, __shfl_xor(mx, 4));
        mx = fmaxf(mx, __shfl_xor(mx, 8));
        v0 = __expf(v0 - mx); v1 = __expf(v1 - mx); v2 = __expf(v2 - mx); v3 = __expf(v3 - mx);
        float s = v0 + v1 + v2 + v3;
        s += __shfl_xor(s, 1); s += __shfl_xor(s, 2); s += __shfl_xor(s, 4); s += __shfl_xor(s, 8);
        const float inv = (proj == 0 ? 0.125f : 1.0f) / s;
        v0 *= inv; v1 *= inv; v2 *= inv; v3 *= inv;
      }
      bf16* o = OUT + (arow + rt * 16 + g * 4 + q) * 512 + w * 64 + li;
      o[0] = (bf16)v0; o[16] = (bf16)v1; o[32] = (bf16)v2; o[48] = (bf16)v3;
    }
  }
}

// ---------------- K2: kv partials = K_h^T V_h over an n-chunk ----------------
__global__ __launch_bounds__(256) void k_kv(const bf16* __restrict__ K, const bf16* __restrict__ V,
                                            float* __restrict__ kvp)
{
  const int mh = blockIdx.x, m = mh >> 3, h = mh & 7;
  const int ns = blockIdx.y;
  __shared__ bf16 Kt[64][40];
  __shared__ bf16 Vt[64][40];
  const int t = threadIdx.x, lane = t & 63, wave = t >> 6;
  const int dq = wave >> 1, eq = wave & 1;
  const int g = lane >> 4, li = lane & 15;
  const int tn = t & 31, d0 = (t >> 5) << 3;
  const size_t rowbase = (size_t)m * 2048 + ns * 512;

  f32x4 acc[2][2] = {};

  for (int nt = 0; nt < 16; ++nt) {
    __syncthreads();
    {
      bf16x8 kr = *(const bf16x8*)(K + (rowbase + nt * 32 + tn) * 512 + h * 64 + d0);
      bf16x8 vr = *(const bf16x8*)(V + (rowbase + nt * 32 + tn) * 512 + h * 64 + d0);
#pragma unroll
      for (int j = 0; j < 8; ++j) Kt[d0 + j][tn] = kr[j];
#pragma unroll
      for (int j = 0; j < 8; ++j) Vt[d0 + j][tn] = vr[j];
    }
    __syncthreads();
    bf16x8 af[2], bfr[2];
#pragma unroll
    for (int dt = 0; dt < 2; ++dt) af[dt]  = *(const bf16x8*)&Kt[dq * 32 + dt * 16 + li][g * 8];
#pragma unroll
    for (int et = 0; et < 2; ++et) bfr[et] = *(const bf16x8*)&Vt[eq * 32 + et * 16 + li][g * 8];
#pragma unroll
    for (int dt = 0; dt < 2; ++dt)
#pragma unroll
      for (int et = 0; et < 2; ++et)
        acc[dt][et] = MFMA16(af[dt], bfr[et], acc[dt][et]);
  }

  float* o = kvp + ((size_t)mh * 4 + ns) * 4096;
#pragma unroll
  for (int dt = 0; dt < 2; ++dt)
#pragma unroll
    for (int et = 0; et < 2; ++et)
#pragma unroll
      for (int q = 0; q < 4; ++q) {
        const int d = dq * 32 + dt * 16 + g * 4 + q;
        const int e = eq * 32 + et * 16 + li;
        o[d * 64 + e] = acc[dt][et][q];
      }
}

// ---------------- K3: WfusedT[m][c][r=h*64+d] = sum_e kv[d][e] * WoT[c][h*64+e] ----------------
__global__ __launch_bounds__(512) void k_wfused(const float* __restrict__ kvp, const bf16* __restrict__ WoT,
                                                bf16* __restrict__ WfT)
{
  const int mh = blockIdx.x, m = mh >> 3, h = mh & 7;
  __shared__ bf16 kvs[64][72];
  const int t = threadIdx.x, lane = t & 63, wave = t >> 6;
  const int g = lane >> 4, li = lane & 15;
  {
    const int d = t >> 3, e0 = (t & 7) << 3;
    const float* p = kvp + (size_t)mh * 16384 + d * 64 + e0;
#pragma unroll
    for (int j = 0; j < 8; ++j) {
      float s = p[j] + p[4096 + j] + p[8192 + j] + p[12288 + j];
      kvs[d][e0 + j] = (bf16)s;
    }
  }
  __syncthreads();
  f32x4 acc[4][4] = {};
#pragma unroll
  for (int kk = 0; kk < 2; ++kk) {
    bf16x8 af[4], bfr[4];
#pragma unroll
    for (int rt = 0; rt < 4; ++rt) {
      const int c = wave * 64 + rt * 16 + li;
      af[rt] = *(const bf16x8*)(WoT + (size_t)c * 512 + h * 64 + kk * 32 + g * 8);
    }
#pragma unroll
    for (int ct = 0; ct < 4; ++ct)
      bfr[ct] = *(const bf16x8*)&kvs[ct * 16 + li][kk * 32 + g * 8];
#pragma unroll
    for (int rt = 0; rt < 4; ++rt)
#pragma unroll
      for (int ct = 0; ct < 4; ++ct)
        acc[rt][ct] = MFMA16(af[rt], bfr[ct], acc[rt][ct]);
  }
  bf16* o = WfT + (size_t)m * 262144;
#pragma unroll
  for (int rt = 0; rt < 4; ++rt)
#pragma unroll
    for (int ct = 0; ct < 4; ++ct)
#pragma unroll
      for (int q = 0; q < 4; ++q) {
        const int c = wave * 64 + rt * 16 + g * 4 + q;
        const int r = h * 64 + ct * 16 + li;
        o[(size_t)c * 512 + r] = (bf16)acc[rt][ct][q];
      }
}

// ---------------- K4: out = Q @ Wfused[m] + bo (2-phase, BK=32) ----------------
// 512 blocks (64 rows), 512 thr = 8 waves; wave w owns cols w*64..+64.
__global__ __launch_bounds__(512, 2) void k_out(const bf16* __restrict__ Q, const bf16* __restrict__ WfT,
                                                const float* __restrict__ bo, float* __restrict__ out)
{
  const int rb = blockIdx.x;
  const int m  = rb >> 5;                      // 32 row-blocks per m
  const bf16* Bm = WfT + (size_t)m * 262144;

  __shared__ bf16 Ab2[2][2048];    // 2 x 4 KB   ([64][32] bf16)
  __shared__ bf16 Bb2[2][16384];   // 2 x 32 KB  ([512][32] bf16)

  const int t = threadIdx.x, lane = t & 63, w = t >> 6;
  const int g = lane >> 4, li = lane & 15;
  const size_t arow = (size_t)rb * 64;

  // A staging (waves 0..3): wave w rows w*16..+16; lane l -> row w*16+(l>>2),
  // slot l&3 holds chunk (l&3)^((l>>2)&3)  (involution with row&3)
  const bf16* asrc = Q + (arow + w * 16 + (lane >> 2)) * 512
                       + (((lane & 3) ^ ((lane >> 2) & 3)) << 3);
  // B staging: same pattern as k_qkv B
  const bf16* bsrc = Bm + (size_t)(w * 64 + (lane >> 2)) * 512
                        + (((lane & 3) ^ ((lane >> 3) & 3)) << 3);

  f32x4 acc[4][4] = {};

  // prologue: stage tile 0
#pragma unroll
  for (int j = 0; j < 4; ++j)
    glds16(bsrc + (size_t)j * 16 * 512, (char*)&Bb2[0][0] + w * 4096 + j * 1024);
  if (w < 4) glds16(asrc, (char*)&Ab2[0][0] + w * 1024);
  asm volatile("s_waitcnt vmcnt(0)" ::: "memory");
  __builtin_amdgcn_s_barrier();

#pragma unroll
  for (int kt = 0; kt < 16; ++kt) {
    const int cur = kt & 1;
    if (kt < 15) {
#pragma unroll
      for (int j = 0; j < 4; ++j)
        glds16(bsrc + (size_t)j * 16 * 512 + (kt + 1) * 32,
               (char*)&Bb2[cur ^ 1][0] + w * 4096 + j * 1024);
      if (w < 4) glds16(asrc + (kt + 1) * 32, (char*)&Ab2[cur ^ 1][0] + w * 1024);
    }
    bf16x8 af[4], bfr[4];
#pragma unroll
    for (int rt = 0; rt < 4; ++rt)
      af[rt] = *(const bf16x8*)&Ab2[cur][(rt * 16 + li) * 32 + (g ^ (li & 3)) * 8];
#pragma unroll
    for (int ct = 0; ct < 4; ++ct)
      bfr[ct] = *(const bf16x8*)&Bb2[cur][(w * 64 + ct * 16 + li) * 32 + (g ^ ((li >> 1) & 3)) * 8];
#pragma unroll
    for (int rt = 0; rt < 4; ++rt)
#pragma unroll
      for (int ct = 0; ct < 4; ++ct)
        acc[rt][ct] = MFMA16(af[rt], bfr[ct], acc[rt][ct]);
    if (kt < 15) {
      asm volatile("s_waitcnt vmcnt(0)" ::: "memory");
      __builtin_amdgcn_s_barrier();
    }
  }

  float bv[4];
#pragma unroll
  for (int ct = 0; ct < 4; ++ct) bv[ct] = bo[w * 64 + ct * 16 + li];
#pragma unroll
  for (int rt = 0; rt < 4; ++rt)
#pragma unroll
    for (int q = 0; q < 4; ++q) {
      float* o = out + (arow + rt * 16 + g * 4 + q) * 512 + w * 64 + li;
      o[0]  = acc[rt][0][q] + bv[0];
      o[16] = acc[rt][1][q] + bv[1];
      o[32] = acc[rt][2][q] + bv[2];
      o[48] = acc[rt][3][q] + bv[3];
    }
}

// ---------------- host ----------------
extern "C" void kernel_launch(void* const* d_in, const int* in_sizes, int n_in,
                              void* d_out, int out_size, void* d_ws, size_t ws_size,
                              hipStream_t stream)
{
  const float* xq = (const float*)d_in[0];
  const float* xk = (const float*)d_in[1];
  const float* xv = (const float*)d_in[2];
  const float* Wq = (const float*)d_in[3];
  const float* Wk = (const float*)d_in[4];
  const float* Wv = (const float*)d_in[5];
  const float* Wo = (const float*)d_in[6];
  const float* bo = (const float*)d_in[7];
  float* out = (float*)d_out;

  char* ws = (char*)d_ws;
  const size_t WT_BYTES  = 512 * 512 * 2;           // 512 KiB each
  const size_t QKV_BYTES = (size_t)32768 * 512 * 2; // 32 MiB each
  bf16*  WqT = (bf16*)(ws);
  bf16*  WkT = (bf16*)(ws + WT_BYTES);
  bf16*  WvT = (bf16*)(ws + 2 * WT_BYTES);
  bf16*  WoT = (bf16*)(ws + 3 * WT_BYTES);
  bf16*  Qb  = (bf16*)(ws + 4 * WT_BYTES);
  bf16*  Kb  = (bf16*)(ws + 4 * WT_BYTES + QKV_BYTES);
  bf16*  Vb  = (bf16*)(ws + 4 * WT_BYTES + 2 * QKV_BYTES);
  float* kvp = (float*)(ws + 4 * WT_BYTES + 3 * QKV_BYTES);  // 8 MiB
  bf16*  WfT = Kb;  // overlay: Kb dead after k_kv

  k_prep  <<<dim3(8, 8, 4),   256, 0, stream>>>(Wq, Wk, Wv, Wo, WqT, WkT, WvT, WoT);
  k_qkv   <<<dim3(512, 1, 3), 512, 0, stream>>>(xq, xk, xv, WqT, WkT, WvT, Qb, Kb, Vb);
  k_kv    <<<dim3(128, 4),    256, 0, stream>>>(Kb, Vb, kvp);
  k_wfused<<<dim3(128),       512, 0, stream>>>(kvp, WoT, WfT);
  k_out   <<<dim3(512),       512, 0, stream>>>(Qb, WfT, bo, out);
}

// Round 9
// 194.763 us; speedup vs baseline: 1.1355x; 1.1355x over previous
//
#include <hip/hip_runtime.h>
#include <hip/hip_bf16.h>

// Linear attention (BaseMultiHeadAttention_21105469292684)
// M=16, N=2048, C=512, H=8, D=64.
//   K0a: proj weights fp32 -> bf16 fragment-major (validated r2/r4)
//   K0b: Wo fp32 -> bf16 transposed WoT[c][k]
//   K1 : Q/K/V: 8 waves, wave tile 64x32 (half-head), BK=32, depth-2 register
//        pipeline (A fp32->LDS dbuf, B frag-major->regs), raw barriers (no vmcnt drain)
//   K2 : kv partials = K_h^T V_h over n-chunks (fp32)
//   K3 : Wfused = blockdiag(kv) @ Wo, emitted fragment-major (validated r4)
//   K4 : out = Q @ Wfused[m] + bo, same structure as K1, fp32 out

typedef __bf16 bf16;
typedef __bf16 bf16x8 __attribute__((ext_vector_type(8)));
typedef __bf16 bf16x4 __attribute__((ext_vector_type(4)));
typedef float  f32x4  __attribute__((ext_vector_type(4)));

#define MFMA16(a, b, c) __builtin_amdgcn_mfma_f32_16x16x32_bf16((a), (b), (c), 0, 0, 0)

#define STEP_SYNC() do { \
  asm volatile("s_waitcnt lgkmcnt(0)" ::: "memory"); \
  __builtin_amdgcn_sched_barrier(0); \
  __builtin_amdgcn_s_barrier(); \
  __builtin_amdgcn_sched_barrier(0); \
} while (0)

__device__ inline bf16x4 cvt4(float4 a) {
  bf16x4 h; h[0] = (bf16)a.x; h[1] = (bf16)a.y; h[2] = (bf16)a.z; h[3] = (bf16)a.w;
  return h;
}

// ---------------- K0a: proj weights -> fragment-major bf16 (r2/r4-validated) ----------------
// element W[k][c]: cg=c>>7, kt64=k>>6, ksub=(k>>5)&1, cb7=(c>>4)&7,
//                  lane=((k>>3)&3)*16+(c&15), j=k&7
// off = cg*65536 + kt64*8192 + ksub*4096 + cb7*512 + lane*8 + j
__global__ __launch_bounds__(256) void k_prep_frag(const float* __restrict__ w0, const float* __restrict__ w1,
                                                   const float* __restrict__ w2,
                                                   bf16* __restrict__ f0, bf16* __restrict__ f1,
                                                   bf16* __restrict__ f2)
{
  const float* W = (blockIdx.z == 0) ? w0 : (blockIdx.z == 1) ? w1 : w2;
  bf16*        F = (blockIdx.z == 0) ? f0 : (blockIdx.z == 1) ? f1 : f2;
  __shared__ float lds[64][68];
  const int t = threadIdx.x;
  const int bx = blockIdx.x, by = blockIdx.y;
  {
    const int r = t >> 2, c0 = (t & 3) << 4;
    const float* src = W + (size_t)(bx * 64 + r) * 512 + by * 64 + c0;
    float4 a = ((const float4*)src)[0], b = ((const float4*)src)[1];
    float4 c = ((const float4*)src)[2], d = ((const float4*)src)[3];
    *(float4*)&lds[r][c0 + 0]  = a; *(float4*)&lds[r][c0 + 4]  = b;
    *(float4*)&lds[r][c0 + 8]  = c; *(float4*)&lds[r][c0 + 12] = d;
  }
  __syncthreads();
#pragma unroll
  for (int it = 0; it < 2; ++it) {
    const int ch = t + it * 256;
    const int kc = ch >> 6, cc = ch & 63;
    bf16x8 v;
#pragma unroll
    for (int j = 0; j < 8; ++j) v[j] = (bf16)lds[kc * 8 + j][cc];
    const int cg   = by >> 1;
    const int cb7  = ((by & 1) << 2) | (cc >> 4);
    const int ksub = kc >> 2, g = kc & 3, li = cc & 15;
    const size_t off = (size_t)cg * 65536 + (size_t)bx * 8192 + ksub * 4096 + cb7 * 512 + (g * 16 + li) * 8;
    *(bf16x8*)(F + off) = v;
  }
}

// ---------------- K0b: Wo -> transposed bf16 WoT[c][k] ----------------
__global__ __launch_bounds__(256) void k_prep_wo(const float* __restrict__ W, bf16* __restrict__ T)
{
  __shared__ float lds[64][68];
  const int t = threadIdx.x;
  const int r = t >> 2, c0 = (t & 3) << 4;
  const float* src = W + (size_t)(blockIdx.x * 64 + r) * 512 + blockIdx.y * 64 + c0;
  float4 f0 = ((const float4*)src)[0];
  float4 f1 = ((const float4*)src)[1];
  float4 f2 = ((const float4*)src)[2];
  float4 f3 = ((const float4*)src)[3];
  *(float4*)&lds[r][c0 + 0]  = f0;
  *(float4*)&lds[r][c0 + 4]  = f1;
  *(float4*)&lds[r][c0 + 8]  = f2;
  *(float4*)&lds[r][c0 + 12] = f3;
  __syncthreads();
  bf16 v[16];
#pragma unroll
  for (int s = 0; s < 16; ++s) v[s] = (bf16)lds[c0 + s][r];
  bf16* dst = T + (size_t)(blockIdx.y * 64 + r) * 512 + blockIdx.x * 64 + c0;
  *(bf16x8*)&dst[0] = *(bf16x8*)&v[0];
  *(bf16x8*)&dst[8] = *(bf16x8*)&v[8];
}

// ---------------- K1: fused projection + per-head softmax ----------------
// 3072 blocks x 512 thr (8 waves). Block = 64 rows x 256 cols (cgrp half of 512).
// Wave w: head = cgrp*4 + (w>>1), half wh = w&1 -> 64 rows x 32 cols, acc[4][2].
// A: fp32 X -> reg (depth-2) -> cvt -> LDS dbuf [2][64][40]. B: frag-major -> regs (depth-2).
// One lgkmcnt(0)+s_barrier per step; global prefetches fly across barriers (counted vmcnt).
__global__ __launch_bounds__(512, 4) void k_qkv(const float* __restrict__ xq, const float* __restrict__ xk,
                                                const float* __restrict__ xv,
                                                const bf16* __restrict__ Fq, const bf16* __restrict__ Fk,
                                                const bf16* __restrict__ Fv,
                                                bf16* __restrict__ Qo, bf16* __restrict__ Ko,
                                                bf16* __restrict__ Vo)
{
  const int wg = blockIdx.x;
  const int o  = (wg & 7) * 384 + (wg >> 3);      // 3072 = 384*8, bijective XCD chunking
  const int proj = o >> 10;                       // 1024 blocks per projection
  const int rem  = o & 1023;
  const int rb = rem >> 1, cgrp = rem & 1;        // (rb,cgrp) adjacent -> same XCD (A L2 reuse)

  const float* X  = (proj == 0) ? xq : (proj == 1) ? xk : xv;
  const bf16*  F  = (proj == 0) ? Fq : (proj == 1) ? Fk : Fv;
  bf16*       OUT = (proj == 0) ? Qo : (proj == 1) ? Ko : Vo;

  __shared__ bf16 As[2][64][40];    // 10 KB
  __shared__ float exm[8][64];
  __shared__ float exs[8][64];

  const int t = threadIdx.x, lane = t & 63, w = t >> 6;
  const int g = lane >> 4, li = lane & 15;
  const int head = cgrp * 4 + (w >> 1), wh = w & 1;
  const size_t arow = (size_t)rb * 64;

  const int ar = t >> 3, ac = (t & 7) << 2;       // A staging: row, col*4
  const float* xp = X + (arow + ar) * 512 + ac;

  const bf16* bp = F + (size_t)(head >> 1) * 65536 + (((head & 1) << 2) + (wh << 1)) * 512 + lane * 8;

  f32x4 acc[4][2] = {};
  float4 xar[2];
  bf16x8 b[2][2];

  // prologue: A(0)->LDS buf0; prefetch A(1),A(2),B(0),B(1)
  {
    float4 x0 = ((const float4*)xp)[0];
    xar[0] = ((const float4*)(xp + 32))[0];
    xar[1] = ((const float4*)(xp + 64))[0];
    b[0][0] = *(const bf16x8*)(bp);
    b[0][1] = *(const bf16x8*)(bp + 512);
    b[1][0] = *(const bf16x8*)(bp + 4096);
    b[1][1] = *(const bf16x8*)(bp + 4096 + 512);
    *(bf16x4*)&As[0][ar][ac] = cvt4(x0);
  }
  STEP_SYNC();

#pragma unroll
  for (int kt = 0; kt < 16; ++kt) {
    const int cur = kt & 1;
    bf16x8 af[4];
#pragma unroll
    for (int rt = 0; rt < 4; ++rt)
      af[rt] = *(const bf16x8*)&As[cur][rt * 16 + li][g * 8];
    if (kt < 15)
      *(bf16x4*)&As[cur ^ 1][ar][ac] = cvt4(xar[cur]);     // A(kt+1), loaded 2 steps ago
    if (kt < 13)
      xar[cur] = ((const float4*)(xp + (kt + 3) * 32))[0]; // A(kt+3) in flight
#pragma unroll
    for (int rt = 0; rt < 4; ++rt) {
      acc[rt][0] = MFMA16(af[rt], b[cur][0], acc[rt][0]);
      acc[rt][1] = MFMA16(af[rt], b[cur][1], acc[rt][1]);
    }
    if (kt < 14) {
      b[cur][0] = *(const bf16x8*)(bp + (kt + 2) * 4096);  // B(kt+2) in flight
      b[cur][1] = *(const bf16x8*)(bp + (kt + 2) * 4096 + 512);
    }
    if (kt < 15) STEP_SYNC();
  }

  // epilogue: softmax over head's 64 cols; wave pair (w, w^1) shares a head
  const int colb = head * 64 + wh * 32 + li;
  if (proj < 2) {
#pragma unroll
    for (int rt = 0; rt < 4; ++rt)
#pragma unroll
      for (int q = 0; q < 4; ++q) {
        float mx = fmaxf(acc[rt][0][q], acc[rt][1][q]);
        mx = fmaxf(mx, __shfl_xor(mx, 1));
        mx = fmaxf(mx, __shfl_xor(mx, 2));
        mx = fmaxf(mx, __shfl_xor(mx, 4));
        mx = fmaxf(mx, __shfl_xor(mx, 8));
        if (li == 0) exm[w][rt * 16 + g * 4 + q] = mx;
      }
    __syncthreads();
#pragma unroll
    for (int rt = 0; rt < 4; ++rt)
#pragma unroll
      for (int q = 0; q < 4; ++q) {
        const int r = rt * 16 + g * 4 + q;
        float mx = fmaxf(exm[w][r], exm[w ^ 1][r]);
        float e0 = __expf(acc[rt][0][q] - mx);
        float e1 = __expf(acc[rt][1][q] - mx);
        acc[rt][0][q] = e0; acc[rt][1][q] = e1;
        float s = e0 + e1;
        s += __shfl_xor(s, 1); s += __shfl_xor(s, 2);
        s += __shfl_xor(s, 4); s += __shfl_xor(s, 8);
        if (li == 0) exs[w][r] = s;
      }
    __syncthreads();
    const float scale = (proj == 0) ? 0.125f : 1.0f;
#pragma unroll
    for (int rt = 0; rt < 4; ++rt)
#pragma unroll
      for (int q = 0; q < 4; ++q) {
        const int r = rt * 16 + g * 4 + q;
        const float inv = scale / (exs[w][r] + exs[w ^ 1][r]);
        bf16* op = OUT + (arow + r) * 512 + colb;
        op[0]  = (bf16)(acc[rt][0][q] * inv);
        op[16] = (bf16)(acc[rt][1][q] * inv);
      }
  } else {
#pragma unroll
    for (int rt = 0; rt < 4; ++rt)
#pragma unroll
      for (int q = 0; q < 4; ++q) {
        const int r = rt * 16 + g * 4 + q;
        bf16* op = OUT + (arow + r) * 512 + colb;
        op[0]  = (bf16)acc[rt][0][q];
        op[16] = (bf16)acc[rt][1][q];
      }
  }
}

// ---------------- K2: kv partials = K_h^T V_h over an n-chunk ----------------
__global__ __launch_bounds__(256) void k_kv(const bf16* __restrict__ K, const bf16* __restrict__ V,
                                            float* __restrict__ kvp)
{
  const int mh = blockIdx.x, m = mh >> 3, h = mh & 7;
  const int ns = blockIdx.y;
  __shared__ bf16 Kt[64][40];
  __shared__ bf16 Vt[64][40];
  const int t = threadIdx.x, lane = t & 63, wave = t >> 6;
  const int dq = wave >> 1, eq = wave & 1;
  const int g = lane >> 4, li = lane & 15;
  const int tn = t & 31, d0 = (t >> 5) << 3;
  const size_t rowbase = (size_t)m * 2048 + ns * 512;

  f32x4 acc[2][2] = {};

  for (int nt = 0; nt < 16; ++nt) {
    __syncthreads();
    {
      bf16x8 kr = *(const bf16x8*)(K + (rowbase + nt * 32 + tn) * 512 + h * 64 + d0);
      bf16x8 vr = *(const bf16x8*)(V + (rowbase + nt * 32 + tn) * 512 + h * 64 + d0);
#pragma unroll
      for (int j = 0; j < 8; ++j) Kt[d0 + j][tn] = kr[j];
#pragma unroll
      for (int j = 0; j < 8; ++j) Vt[d0 + j][tn] = vr[j];
    }
    __syncthreads();
    bf16x8 af[2], bfr[2];
#pragma unroll
    for (int dt = 0; dt < 2; ++dt) af[dt]  = *(const bf16x8*)&Kt[dq * 32 + dt * 16 + li][g * 8];
#pragma unroll
    for (int et = 0; et < 2; ++et) bfr[et] = *(const bf16x8*)&Vt[eq * 32 + et * 16 + li][g * 8];
#pragma unroll
    for (int dt = 0; dt < 2; ++dt)
#pragma unroll
      for (int et = 0; et < 2; ++et)
        acc[dt][et] = MFMA16(af[dt], bfr[et], acc[dt][et]);
  }

  float* o = kvp + ((size_t)mh * 4 + ns) * 4096;
#pragma unroll
  for (int dt = 0; dt < 2; ++dt)
#pragma unroll
    for (int et = 0; et < 2; ++et)
#pragma unroll
      for (int q = 0; q < 4; ++q) {
        const int d = dq * 32 + dt * 16 + g * 4 + q;
        const int e = eq * 32 + et * 16 + li;
        o[d * 64 + e] = acc[dt][et][q];
      }
}

// ---------------- K3: Wfused = blockdiag(kv) @ Wo, frag-major out (validated r4) ----------------
__global__ __launch_bounds__(512) void k_wfused(const float* __restrict__ kvp, const bf16* __restrict__ WoT,
                                                bf16* __restrict__ WfF)
{
  const int mh = blockIdx.x, m = mh >> 3, h = mh & 7;
  __shared__ bf16 kvs[64][72];
  const int t = threadIdx.x, lane = t & 63, wv = t >> 6;
  const int g = lane >> 4, li = lane & 15;
  {
    const int d = t >> 3, e0 = (t & 7) << 3;
    const float* p = kvp + (size_t)mh * 16384 + d * 64 + e0;
#pragma unroll
    for (int j = 0; j < 8; ++j) {
      float s = p[j] + p[4096 + j] + p[8192 + j] + p[12288 + j];
      kvs[d][e0 + j] = (bf16)s;
    }
  }
  __syncthreads();
  f32x4 acc[4][4] = {};
#pragma unroll
  for (int kk = 0; kk < 2; ++kk) {
    bf16x8 a_kv[4], b_wo[4];
#pragma unroll
    for (int rt = 0; rt < 4; ++rt)
      a_kv[rt] = *(const bf16x8*)&kvs[rt * 16 + li][kk * 32 + g * 8];
#pragma unroll
    for (int ct = 0; ct < 4; ++ct) {
      const int cout = wv * 64 + ct * 16 + li;
      b_wo[ct] = *(const bf16x8*)(WoT + (size_t)cout * 512 + h * 64 + kk * 32 + g * 8);
    }
#pragma unroll
    for (int rt = 0; rt < 4; ++rt)
#pragma unroll
      for (int ct = 0; ct < 4; ++ct)
        acc[rt][ct] = MFMA16(a_kv[rt], b_wo[ct], acc[rt][ct]);
  }
  // emit fragment-major: k = h*64 + rt*16 + g*4 + q, col = wv*64 + ct*16 + li
  bf16* o = WfF + (size_t)m * 262144;
#pragma unroll
  for (int rt = 0; rt < 4; ++rt)
#pragma unroll
    for (int ct = 0; ct < 4; ++ct) {
      const int cgct  = wv * 4 + ct;
      const int cg    = cgct >> 3, cb7 = cgct & 7;
      const int lane2 = ((rt & 1) * 2 + (g >> 1)) * 16 + li;
      const size_t off = (size_t)cg * 65536 + (size_t)h * 8192 + (rt >> 1) * 4096
                       + cb7 * 512 + lane2 * 8 + (g & 1) * 4;
      bf16x4 v;
#pragma unroll
      for (int q = 0; q < 4; ++q) v[q] = (bf16)acc[rt][ct][q];
      *(bf16x4*)(o + off) = v;
    }
}

// ---------------- K4: out = Q @ Wfused[m] + bo (same pipeline as K1) ----------------
// 1024 blocks x 512 thr. Block = 64 rows x 256 cols; wave 64x32; fp32 out.
__global__ __launch_bounds__(512, 4) void k_out(const bf16* __restrict__ Q, const bf16* __restrict__ WfF,
                                                const float* __restrict__ bo, float* __restrict__ out)
{
  const int wg = blockIdx.x;
  const int o  = (wg & 7) * 128 + (wg >> 3);      // 1024 = 128*8
  const int rb = o >> 1, cgrp = o & 1;
  const int m  = rb >> 5;
  const bf16* Fm = WfF + (size_t)m * 262144;

  __shared__ bf16 As[2][64][40];

  const int t = threadIdx.x, lane = t & 63, w = t >> 6;
  const int g = lane >> 4, li = lane & 15;
  const int head = cgrp * 4 + (w >> 1), wh = w & 1;
  const size_t arow = (size_t)rb * 64;

  const int ar = t >> 3, ac = (t & 7) << 2;
  const bf16* qp = Q + (arow + ar) * 512 + ac;
  const bf16* bp = Fm + (size_t)(head >> 1) * 65536 + (((head & 1) << 2) + (wh << 1)) * 512 + lane * 8;

  f32x4 acc[4][2] = {};
  bf16x4 xar[2];
  bf16x8 b[2][2];

  {
    bf16x4 x0 = *(const bf16x4*)(qp);
    xar[0] = *(const bf16x4*)(qp + 32);
    xar[1] = *(const bf16x4*)(qp + 64);
    b[0][0] = *(const bf16x8*)(bp);
    b[0][1] = *(const bf16x8*)(bp + 512);
    b[1][0] = *(const bf16x8*)(bp + 4096);
    b[1][1] = *(const bf16x8*)(bp + 4096 + 512);
    *(bf16x4*)&As[0][ar][ac] = x0;
  }
  STEP_SYNC();

#pragma unroll
  for (int kt = 0; kt < 16; ++kt) {
    const int cur = kt & 1;
    bf16x8 af[4];
#pragma unroll
    for (int rt = 0; rt < 4; ++rt)
      af[rt] = *(const bf16x8*)&As[cur][rt * 16 + li][g * 8];
    if (kt < 15)
      *(bf16x4*)&As[cur ^ 1][ar][ac] = xar[cur];
    if (kt < 13)
      xar[cur] = *(const bf16x4*)(qp + (kt + 3) * 32);
#pragma unroll
    for (int rt = 0; rt < 4; ++rt) {
      acc[rt][0] = MFMA16(af[rt], b[cur][0], acc[rt][0]);
      acc[rt][1] = MFMA16(af[rt], b[cur][1], acc[rt][1]);
    }
    if (kt < 14) {
      b[cur][0] = *(const bf16x8*)(bp + (kt + 2) * 4096);
      b[cur][1] = *(const bf16x8*)(bp + (kt + 2) * 4096 + 512);
    }
    if (kt < 15) STEP_SYNC();
  }

  const int colb = head * 64 + wh * 32 + li;
  const float b0 = bo[colb], b1 = bo[colb + 16];
#pragma unroll
  for (int rt = 0; rt < 4; ++rt)
#pragma unroll
    for (int q = 0; q < 4; ++q) {
      float* op = out + (arow + rt * 16 + g * 4 + q) * 512 + colb;
      op[0]  = acc[rt][0][q] + b0;
      op[16] = acc[rt][1][q] + b1;
    }
}

// ---------------- host ----------------
extern "C" void kernel_launch(void* const* d_in, const int* in_sizes, int n_in,
                              void* d_out, int out_size, void* d_ws, size_t ws_size,
                              hipStream_t stream)
{
  const float* xq = (const float*)d_in[0];
  const float* xk = (const float*)d_in[1];
  const float* xv = (const float*)d_in[2];
  const float* Wq = (const float*)d_in[3];
  const float* Wk = (const float*)d_in[4];
  const float* Wv = (const float*)d_in[5];
  const float* Wo = (const float*)d_in[6];
  const float* bo = (const float*)d_in[7];
  float* out = (float*)d_out;

  char* ws = (char*)d_ws;
  const size_t WT_BYTES  = 512 * 512 * 2;           // 512 KiB
  const size_t QKV_BYTES = (size_t)32768 * 512 * 2; // 32 MiB
  bf16*  WFq = (bf16*)(ws);
  bf16*  WFk = (bf16*)(ws + WT_BYTES);
  bf16*  WFv = (bf16*)(ws + 2 * WT_BYTES);
  bf16*  WoT = (bf16*)(ws + 3 * WT_BYTES);
  bf16*  Qb  = (bf16*)(ws + 4 * WT_BYTES);
  bf16*  Kb  = (bf16*)(ws + 4 * WT_BYTES + QKV_BYTES);
  bf16*  Vb  = (bf16*)(ws + 4 * WT_BYTES + 2 * QKV_BYTES);
  float* kvp = (float*)(ws + 4 * WT_BYTES + 3 * QKV_BYTES);  // 8 MiB
  bf16*  WfF = Kb;  // overlay: Kb dead after k_kv

  k_prep_frag<<<dim3(8, 8, 3), 256, 0, stream>>>(Wq, Wk, Wv, WFq, WFk, WFv);
  k_prep_wo  <<<dim3(8, 8),    256, 0, stream>>>(Wo, WoT);
  k_qkv      <<<dim3(3072),    512, 0, stream>>>(xq, xk, xv, WFq, WFk, WFv, Qb, Kb, Vb);
  k_kv       <<<dim3(128, 4),  256, 0, stream>>>(Kb, Vb, kvp);
  k_wfused   <<<dim3(128),     512, 0, stream>>>(kvp, WoT, WfF);
  k_out      <<<dim3(1024),    512, 0, stream>>>(Qb, WfF, bo, out);
}

// Round 10
// 165.241 us; speedup vs baseline: 1.3383x; 1.1787x over previous
//
#include <hip/hip_runtime.h>
#include <hip/hip_bf16.h>

// Linear attention (BaseMultiHeadAttention_21105469292684)
// M=16, N=2048, C=512, H=8, D=64.
//   K0 : weights fp32 -> bf16 transposed WT[col][k] (all 4)
//   K1 : Q/K/V = softmax-ish(x @ W): r7 mechanics at BM=128 x BN=256 (8 waves 2x4,
//        wave tile 64x64), BK=32, A reg-staged fp32->bf16 pad-40, B gload_lds+involution
//   K2 : kv partials = K_h^T V_h over n-chunks (fp32)           [r7 verbatim]
//   K3 : WfusedT[m][c][r] = sum_e kv[m,h,d,e] * Wo[h*64+e][c]   [r7 verbatim]
//   K4 : out = Q @ Wfused[m] + bo: same BM=128 x BN=256 geometry, both operands
//        gload_lds (Q already bf16), fp32 out

typedef __bf16 bf16;
typedef __bf16 bf16x8 __attribute__((ext_vector_type(8)));
typedef __bf16 bf16x4 __attribute__((ext_vector_type(4)));
typedef float  f32x4  __attribute__((ext_vector_type(4)));

#define MFMA16(a, b, c) __builtin_amdgcn_mfma_f32_16x16x32_bf16((a), (b), (c), 0, 0, 0)

__device__ inline bf16x8 cvt8(float4 a, float4 b) {
  bf16x8 h;
  h[0] = (bf16)a.x; h[1] = (bf16)a.y; h[2] = (bf16)a.z; h[3] = (bf16)a.w;
  h[4] = (bf16)b.x; h[5] = (bf16)b.y; h[6] = (bf16)b.z; h[7] = (bf16)b.w;
  return h;
}

__device__ inline void glds16(const void* g, void* l) {
  __builtin_amdgcn_global_load_lds((const __attribute__((address_space(1))) void*)g,
                                   (__attribute__((address_space(3))) void*)l, 16, 0, 0);
}

// ---------------- K0: transpose + convert weights (512x512 each) ----------------
__global__ __launch_bounds__(256) void k_prep(const float* __restrict__ w0, const float* __restrict__ w1,
                                              const float* __restrict__ w2, const float* __restrict__ w3,
                                              bf16* __restrict__ t0, bf16* __restrict__ t1,
                                              bf16* __restrict__ t2, bf16* __restrict__ t3)
{
  const float* W = (blockIdx.z == 0) ? w0 : (blockIdx.z == 1) ? w1 : (blockIdx.z == 2) ? w2 : w3;
  bf16*        T = (blockIdx.z == 0) ? t0 : (blockIdx.z == 1) ? t1 : (blockIdx.z == 2) ? t2 : t3;
  __shared__ float lds[64][68];
  const int t = threadIdx.x;
  const int r = t >> 2, c0 = (t & 3) << 4;
  const float* src = W + (size_t)(blockIdx.x * 64 + r) * 512 + blockIdx.y * 64 + c0;
  float4 f0 = ((const float4*)src)[0];
  float4 f1 = ((const float4*)src)[1];
  float4 f2 = ((const float4*)src)[2];
  float4 f3 = ((const float4*)src)[3];
  *(float4*)&lds[r][c0 + 0]  = f0;
  *(float4*)&lds[r][c0 + 4]  = f1;
  *(float4*)&lds[r][c0 + 8]  = f2;
  *(float4*)&lds[r][c0 + 12] = f3;
  __syncthreads();
  bf16 v[16];
#pragma unroll
  for (int s = 0; s < 16; ++s) v[s] = (bf16)lds[c0 + s][r];
  bf16* dst = T + (size_t)(blockIdx.y * 64 + r) * 512 + blockIdx.x * 64 + c0;
  *(bf16x8*)&dst[0] = *(bf16x8*)&v[0];
  *(bf16x8*)&dst[8] = *(bf16x8*)&v[8];
}

// ---------------- K1: fused projection + per-head softmax (BM=128, BN=256) ----------------
// 1536 blocks (3 proj x 256 rowb x 2 cb), 512 thr = 8 waves (2 row x 4 col), wave 64x64.
// Wave (wr,wc): rows rb*128+wr*64..+64, cols cb*256+wc*64..+64 = head cb*4+wc.
// A: fp32 -> reg -> bf16 As[128][40] (pad: 2-way banks). B: gload_lds Bs[256][32]
// with involution chunk swizzle (slot s at row r holds chunk s^((r>>1)&3)).
__global__ __launch_bounds__(512) void k_qkv(const float* __restrict__ xq, const float* __restrict__ xk,
                                             const float* __restrict__ xv,
                                             const bf16* __restrict__ WqT, const bf16* __restrict__ WkT,
                                             const bf16* __restrict__ WvT,
                                             bf16* __restrict__ Qo, bf16* __restrict__ Ko,
                                             bf16* __restrict__ Vo)
{
  const int wg = blockIdx.x;
  const int o  = (wg & 7) * 192 + (wg >> 3);    // 1536 = 192*8, bijective XCD chunking
  const int proj = o >> 9;                      // 512 blocks per projection
  const int rem  = o & 511;
  const int rb = rem >> 1, cb = rem & 1;        // (rb,cb) adjacent -> same XCD (A L2 reuse)

  const float* X  = (proj == 0) ? xq  : (proj == 1) ? xk  : xv;
  const bf16*  WT = (proj == 0) ? WqT : (proj == 1) ? WkT : WvT;
  bf16*       OUT = (proj == 0) ? Qo  : (proj == 1) ? Ko  : Vo;

  __shared__ bf16 As[128][40];    // 10 KB
  __shared__ bf16 Bs[256 * 32];   // 16 KB, linear (gload_lds dest)

  const int t = threadIdx.x;
  const int lane = t & 63, w = t >> 6;
  const int wr = w >> 2, wc = w & 3;
  const int g = lane >> 4, li = lane & 15;
  const size_t arow = (size_t)rb * 128;

  // A staging: thread -> row t>>2, 8 floats at col (t&3)*8
  const int ar = t >> 2, ac = (t & 3) << 3;
  const float* xp = X + (arow + ar) * 512 + ac;

  // B staging: wave w stages rows (block B-slice) w*32..+32; lane l -> row w*32+(l>>2),
  // slot l&3 holds source chunk (l&3)^((l>>3)&3)  (involution with (row>>1)&3)
  const bf16* bsrc = WT + (size_t)(cb * 256 + w * 32 + (lane >> 2)) * 512
                        + (((lane & 3) ^ ((lane >> 3) & 3)) << 3);
  char* bdst = (char*)&Bs[0] + w * 2048;        // wave-uniform dest base (32 rows = 2 KB)
  const int bslot = g ^ ((li >> 1) & 3);        // read-side slot

  f32x4 acc[4][4] = {};
  float4 xa0 = ((const float4*)xp)[0];          // kt=0 A fragment (8 floats)
  float4 xa1 = ((const float4*)xp)[1];

  for (int kt = 0; kt < 16; ++kt) {
    __syncthreads();                            // (1) readers done with prev tiles
    *(bf16x8*)&As[ar][ac] = cvt8(xa0, xa1);     // write A (cvt in reg, 16B ds_write)
#pragma unroll
    for (int j = 0; j < 2; ++j)                 // stage B slice (2 x 1KB per wave)
      glds16(bsrc + (size_t)j * 16 * 512 + kt * 32, bdst + j * 1024);
    __syncthreads();                            // (2) staging visible
    if (kt < 15) {                              // T14: next A-load flies under compute
      xa0 = ((const float4*)(xp + (kt + 1) * 32))[0];
      xa1 = ((const float4*)(xp + (kt + 1) * 32))[1];
    }
    bf16x8 af[4], bfr[4];
#pragma unroll
    for (int rt = 0; rt < 4; ++rt)
      af[rt] = *(const bf16x8*)&As[wr * 64 + rt * 16 + li][g * 8];
#pragma unroll
    for (int ct = 0; ct < 4; ++ct)
      bfr[ct] = *(const bf16x8*)&Bs[(wc * 64 + ct * 16 + li) * 32 + bslot * 8];
#pragma unroll
    for (int rt = 0; rt < 4; ++rt)
#pragma unroll
      for (int ct = 0; ct < 4; ++ct)
        acc[rt][ct] = MFMA16(af[rt], bfr[ct], acc[rt][ct]);
  }

  // epilogue: softmax over this wave's head (64 cols = 4 ct x 16 li)
#pragma unroll
  for (int rt = 0; rt < 4; ++rt) {
#pragma unroll
    for (int q = 0; q < 4; ++q) {
      float v0 = acc[rt][0][q], v1 = acc[rt][1][q], v2 = acc[rt][2][q], v3 = acc[rt][3][q];
      if (proj < 2) {
        float mx = fmaxf(fmaxf(v0, v1), fmaxf(v2, v3));
        mx = fmaxf(mx, __shfl_xor(mx, 1));
        mx = fmaxf(mx, __shfl_xor(mx, 2));
        mx = fmaxf(mx, __shfl_xor(mx, 4));
        mx = fmaxf(mx, __shfl_xor(mx, 8));
        v0 = __expf(v0 - mx); v1 = __expf(v1 - mx); v2 = __expf(v2 - mx); v3 = __expf(v3 - mx);
        float s = v0 + v1 + v2 + v3;
        s += __shfl_xor(s, 1); s += __shfl_xor(s, 2); s += __shfl_xor(s, 4); s += __shfl_xor(s, 8);
        const float inv = (proj == 0 ? 0.125f : 1.0f) / s;
        v0 *= inv; v1 *= inv; v2 *= inv; v3 *= inv;
      }
      bf16* op = OUT + (arow + wr * 64 + rt * 16 + g * 4 + q) * 512 + cb * 256 + wc * 64 + li;
      op[0] = (bf16)v0; op[16] = (bf16)v1; op[32] = (bf16)v2; op[48] = (bf16)v3;
    }
  }
}

// ---------------- K2: kv partials = K_h^T V_h over an n-chunk ----------------
__global__ __launch_bounds__(256) void k_kv(const bf16* __restrict__ K, const bf16* __restrict__ V,
                                            float* __restrict__ kvp)
{
  const int mh = blockIdx.x, m = mh >> 3, h = mh & 7;
  const int ns = blockIdx.y;
  __shared__ bf16 Kt[64][40];
  __shared__ bf16 Vt[64][40];
  const int t = threadIdx.x, lane = t & 63, wave = t >> 6;
  const int dq = wave >> 1, eq = wave & 1;
  const int g = lane >> 4, li = lane & 15;
  const int tn = t & 31, d0 = (t >> 5) << 3;
  const size_t rowbase = (size_t)m * 2048 + ns * 512;

  f32x4 acc[2][2] = {};

  for (int nt = 0; nt < 16; ++nt) {
    __syncthreads();
    {
      bf16x8 kr = *(const bf16x8*)(K + (rowbase + nt * 32 + tn) * 512 + h * 64 + d0);
      bf16x8 vr = *(const bf16x8*)(V + (rowbase + nt * 32 + tn) * 512 + h * 64 + d0);
#pragma unroll
      for (int j = 0; j < 8; ++j) Kt[d0 + j][tn] = kr[j];
#pragma unroll
      for (int j = 0; j < 8; ++j) Vt[d0 + j][tn] = vr[j];
    }
    __syncthreads();
    bf16x8 af[2], bfr[2];
#pragma unroll
    for (int dt = 0; dt < 2; ++dt) af[dt]  = *(const bf16x8*)&Kt[dq * 32 + dt * 16 + li][g * 8];
#pragma unroll
    for (int et = 0; et < 2; ++et) bfr[et] = *(const bf16x8*)&Vt[eq * 32 + et * 16 + li][g * 8];
#pragma unroll
    for (int dt = 0; dt < 2; ++dt)
#pragma unroll
      for (int et = 0; et < 2; ++et)
        acc[dt][et] = MFMA16(af[dt], bfr[et], acc[dt][et]);
  }

  float* o = kvp + ((size_t)mh * 4 + ns) * 4096;
#pragma unroll
  for (int dt = 0; dt < 2; ++dt)
#pragma unroll
    for (int et = 0; et < 2; ++et)
#pragma unroll
      for (int q = 0; q < 4; ++q) {
        const int d = dq * 32 + dt * 16 + g * 4 + q;
        const int e = eq * 32 + et * 16 + li;
        o[d * 64 + e] = acc[dt][et][q];
      }
}

// ---------------- K3: WfusedT[m][c][r=h*64+d] = sum_e kv[d][e] * WoT[c][h*64+e] ----------------
__global__ __launch_bounds__(512) void k_wfused(const float* __restrict__ kvp, const bf16* __restrict__ WoT,
                                                bf16* __restrict__ WfT)
{
  const int mh = blockIdx.x, m = mh >> 3, h = mh & 7;
  __shared__ bf16 kvs[64][72];
  const int t = threadIdx.x, lane = t & 63, wave = t >> 6;
  const int g = lane >> 4, li = lane & 15;
  {
    const int d = t >> 3, e0 = (t & 7) << 3;
    const float* p = kvp + (size_t)mh * 16384 + d * 64 + e0;
#pragma unroll
    for (int j = 0; j < 8; ++j) {
      float s = p[j] + p[4096 + j] + p[8192 + j] + p[12288 + j];
      kvs[d][e0 + j] = (bf16)s;
    }
  }
  __syncthreads();
  f32x4 acc[4][4] = {};
#pragma unroll
  for (int kk = 0; kk < 2; ++kk) {
    bf16x8 af[4], bfr[4];
#pragma unroll
    for (int rt = 0; rt < 4; ++rt) {
      const int c = wave * 64 + rt * 16 + li;
      af[rt] = *(const bf16x8*)(WoT + (size_t)c * 512 + h * 64 + kk * 32 + g * 8);
    }
#pragma unroll
    for (int ct = 0; ct < 4; ++ct)
      bfr[ct] = *(const bf16x8*)&kvs[ct * 16 + li][kk * 32 + g * 8];
#pragma unroll
    for (int rt = 0; rt < 4; ++rt)
#pragma unroll
      for (int ct = 0; ct < 4; ++ct)
        acc[rt][ct] = MFMA16(af[rt], bfr[ct], acc[rt][ct]);
  }
  bf16* o = WfT + (size_t)m * 262144;
#pragma unroll
  for (int rt = 0; rt < 4; ++rt)
#pragma unroll
    for (int ct = 0; ct < 4; ++ct)
#pragma unroll
      for (int q = 0; q < 4; ++q) {
        const int c = wave * 64 + rt * 16 + g * 4 + q;
        const int r = h * 64 + ct * 16 + li;
        o[(size_t)c * 512 + r] = (bf16)acc[rt][ct][q];
      }
}

// ---------------- K4: out = Q @ Wfused[m] + bo (BM=128, BN=256, all-glds) ----------------
// 512 blocks (256 rowb x 2 cb), 512 thr = 8 waves (2x4), wave 64x64. fp32 out.
__global__ __launch_bounds__(512) void k_out(const bf16* __restrict__ Q, const bf16* __restrict__ WfT,
                                             const float* __restrict__ bo, float* __restrict__ out)
{
  const int wg = blockIdx.x;
  const int o  = (wg & 7) * 64 + (wg >> 3);     // 512 = 64*8, bijective
  const int rb = o >> 1, cb = o & 1;
  const int m  = rb >> 4;                       // 16 row-blocks (128 rows) per m
  const bf16* Bm = WfT + (size_t)m * 262144;

  __shared__ bf16 As2[128 * 32];   // 8 KB, linear
  __shared__ bf16 Bs2[256 * 32];   // 16 KB, linear

  const int t = threadIdx.x, lane = t & 63, w = t >> 6;
  const int wr = w >> 2, wc = w & 3;
  const int g = lane >> 4, li = lane & 15;
  const size_t arow = (size_t)rb * 128;

  const int schunk = ((lane & 3) ^ ((lane >> 3) & 3)) << 3;
  // A: wave w stages rows w*16..+16 (1 glds/wave/step)
  const bf16* asrc = Q + (arow + w * 16 + (lane >> 2)) * 512 + schunk;
  // B: wave w stages B-rows (out-cols) w*32..+32 (2 glds/wave/step)
  const bf16* bsrc = Bm + (size_t)(cb * 256 + w * 32 + (lane >> 2)) * 512 + schunk;
  char* adst = (char*)&As2[0] + w * 1024;
  char* bdst = (char*)&Bs2[0] + w * 2048;
  const int slot = g ^ ((li >> 1) & 3);

  f32x4 acc[4][4] = {};

  for (int kt = 0; kt < 16; ++kt) {
    __syncthreads();
    glds16(asrc + kt * 32, adst);
#pragma unroll
    for (int j = 0; j < 2; ++j)
      glds16(bsrc + (size_t)j * 16 * 512 + kt * 32, bdst + j * 1024);
    __syncthreads();
    bf16x8 af[4], bfr[4];
#pragma unroll
    for (int rt = 0; rt < 4; ++rt)
      af[rt] = *(const bf16x8*)&As2[(wr * 64 + rt * 16 + li) * 32 + slot * 8];
#pragma unroll
    for (int ct = 0; ct < 4; ++ct)
      bfr[ct] = *(const bf16x8*)&Bs2[(wc * 64 + ct * 16 + li) * 32 + slot * 8];
#pragma unroll
    for (int rt = 0; rt < 4; ++rt)
#pragma unroll
      for (int ct = 0; ct < 4; ++ct)
        acc[rt][ct] = MFMA16(af[rt], bfr[ct], acc[rt][ct]);
  }

  float bv[4];
#pragma unroll
  for (int ct = 0; ct < 4; ++ct) bv[ct] = bo[cb * 256 + wc * 64 + ct * 16 + li];
#pragma unroll
  for (int rt = 0; rt < 4; ++rt)
#pragma unroll
    for (int q = 0; q < 4; ++q) {
      float* op = out + (arow + wr * 64 + rt * 16 + g * 4 + q) * 512 + cb * 256 + wc * 64 + li;
      op[0]  = acc[rt][0][q] + bv[0];
      op[16] = acc[rt][1][q] + bv[1];
      op[32] = acc[rt][2][q] + bv[2];
      op[48] = acc[rt][3][q] + bv[3];
    }
}

// ---------------- host ----------------
extern "C" void kernel_launch(void* const* d_in, const int* in_sizes, int n_in,
                              void* d_out, int out_size, void* d_ws, size_t ws_size,
                              hipStream_t stream)
{
  const float* xq = (const float*)d_in[0];
  const float* xk = (const float*)d_in[1];
  const float* xv = (const float*)d_in[2];
  const float* Wq = (const float*)d_in[3];
  const float* Wk = (const float*)d_in[4];
  const float* Wv = (const float*)d_in[5];
  const float* Wo = (const float*)d_in[6];
  const float* bo = (const float*)d_in[7];
  float* out = (float*)d_out;

  char* ws = (char*)d_ws;
  const size_t WT_BYTES  = 512 * 512 * 2;           // 512 KiB each
  const size_t QKV_BYTES = (size_t)32768 * 512 * 2; // 32 MiB each
  bf16*  WqT = (bf16*)(ws);
  bf16*  WkT = (bf16*)(ws + WT_BYTES);
  bf16*  WvT = (bf16*)(ws + 2 * WT_BYTES);
  bf16*  WoT = (bf16*)(ws + 3 * WT_BYTES);
  bf16*  Qb  = (bf16*)(ws + 4 * WT_BYTES);
  bf16*  Kb  = (bf16*)(ws + 4 * WT_BYTES + QKV_BYTES);
  bf16*  Vb  = (bf16*)(ws + 4 * WT_BYTES + 2 * QKV_BYTES);
  float* kvp = (float*)(ws + 4 * WT_BYTES + 3 * QKV_BYTES);  // 8 MiB
  bf16*  WfT = Kb;  // overlay: Kb dead after k_kv

  k_prep  <<<dim3(8, 8, 4), 256, 0, stream>>>(Wq, Wk, Wv, Wo, WqT, WkT, WvT, WoT);
  k_qkv   <<<dim3(1536),    512, 0, stream>>>(xq, xk, xv, WqT, WkT, WvT, Qb, Kb, Vb);
  k_kv    <<<dim3(128, 4),  256, 0, stream>>>(Kb, Vb, kvp);
  k_wfused<<<dim3(128),     512, 0, stream>>>(kvp, WoT, WfT);
  k_out   <<<dim3(512),     512, 0, stream>>>(Qb, WfT, bo, out);
}